// Round 3
// baseline (111.352 us; speedup 1.0000x reference)
//
#include <hip/hip_runtime.h>
#include <hip/hip_bf16.h>
#include <stdint.h>

// covpool: y[b] = (1/M) * Xc[b] * Xc[b]^T,  Xc = row-centered x, B=64, dim=512, M=256.
// Pass 1 centers + scales by 1/16 ((1/16)^2 = 1/M folds into the product), cvt bf16.
// Pass 2: batched bf16 MFMA SYRK, m97 structure + XOR bank-conflict swizzle.

typedef __attribute__((ext_vector_type(8))) short bf16x8;   // 8 bf16 = 4 VGPRs
typedef __attribute__((ext_vector_type(4))) float f32x4;    // MFMA 16x16 accumulator

static __device__ __forceinline__ unsigned short f2bf(float f) {
    union { float f; uint32_t u; } c; c.f = f;
    uint32_t u = c.u;
    return (unsigned short)((u + 0x7FFFu + ((u >> 16) & 1u)) >> 16);  // RNE
}

// ---------------- Pass 1: center rows, scale 1/16, cvt bf16 ----------------
__global__ __launch_bounds__(256) void center_bf16(const float* __restrict__ x,
                                                   unsigned short* __restrict__ xb) {
    const int wave = threadIdx.x >> 6;
    const int lane = threadIdx.x & 63;
    const int row  = blockIdx.x * 4 + wave;          // 0..32767
    const f32x4 v = __builtin_nontemporal_load(((const f32x4*)(x + (size_t)row * 256)) + lane);
    float s = v.x + v.y + v.z + v.w;
#pragma unroll
    for (int off = 32; off > 0; off >>= 1)
        s += __shfl_xor(s, off, 64);
    const float mean = s * (1.0f / 256.0f);
    const float sc = 0.0625f;                        // 1/16
    ushort4 o;
    o.x = f2bf((v.x - mean) * sc);
    o.y = f2bf((v.y - mean) * sc);
    o.z = f2bf((v.z - mean) * sc);
    o.w = f2bf((v.w - mean) * sc);
    ((ushort4*)(xb + (size_t)row * 256))[lane] = o;  // cached: re-read by pass 2
}

// ---------------- Pass 2: batched SYRK, 128x128 tile, BK=32 ----------------
static __device__ __forceinline__ void gl_lds16(const unsigned short* g, unsigned short* l) {
    __builtin_amdgcn_global_load_lds(
        (const __attribute__((address_space(1))) unsigned int*)g,
        (__attribute__((address_space(3))) unsigned int*)l,
        16, 0, 0);
}

__global__ __launch_bounds__(256) void syrk_bf16(const unsigned short* __restrict__ xb,
                                                 float* __restrict__ y) {
    __shared__ unsigned short As[128 * 32];   // [row][k], 16B chunk c holds global
    __shared__ unsigned short Bs[128 * 32];   // chunk c ^ ((row>>1)&3)  (bank swizzle)

    // XCD swizzle: all 16 tiles of batch b land on XCD b>>3; 8 batches/XCD.
    const int xcd  = blockIdx.x & 7;
    const int j    = blockIdx.x >> 3;        // 0..127
    const int b    = xcd * 8 + (j >> 4);     // 0..63
    const int tile = j & 15;
    const int tm = tile >> 2, tn = tile & 3;

    const unsigned short* Abase = xb + ((size_t)b * 512 + tm * 128) * 256;
    const unsigned short* Bbase = xb + ((size_t)b * 512 + tn * 128) * 256;

    const int tid  = threadIdx.x;
    const int lane = tid & 63;
    const int wave = tid >> 6;
    const int wm = (wave >> 1) * 64;         // wave's 64x64 subtile
    const int wn = (wave & 1) * 64;

    f32x4 acc[4][4] = {};

    const int rl = lane & 15;
    // swizzled 16B-chunk to read for logical chunk q=(lane>>4) at row rl:
    const int swl = ((lane >> 4) ^ ((rl >> 1) & 3)) * 8;   // in shorts

    for (int kk = 0; kk < 256; kk += 32) {
        __syncthreads();
#pragma unroll
        for (int t = 0; t < 2; ++t) {
            const int e   = t * 256 + tid;           // 0..511
            const int row = e >> 2;                  // 0..127
            const int g   = ((e & 3) ^ ((e >> 3) & 3)) * 8; // swizzled global chunk (shorts)
            // LDS dst byte offset e*16 = wave-uniform base + lane*16 (HW requirement);
            // swizzle is applied to the SOURCE address (same addr set per wave -> free).
            gl_lds16(Abase + row * 256 + kk + g, As + e * 8);
            gl_lds16(Bbase + row * 256 + kk + g, Bs + e * 8);
        }
        __syncthreads();

        bf16x8 af[4], bfr[4];
#pragma unroll
        for (int i = 0; i < 4; ++i)
            af[i] = *(const bf16x8*)(As + (wm + i * 16 + rl) * 32 + swl);
#pragma unroll
        for (int jj = 0; jj < 4; ++jj)
            bfr[jj] = *(const bf16x8*)(Bs + (wn + jj * 16 + rl) * 32 + swl);
#pragma unroll
        for (int i = 0; i < 4; ++i)
#pragma unroll
            for (int jj = 0; jj < 4; ++jj)
                acc[i][jj] = __builtin_amdgcn_mfma_f32_16x16x32_bf16(
                    af[i], bfr[jj], acc[i][jj], 0, 0, 0);
    }

    // Epilogue: C/D layout col=lane&15, row=(lane>>4)*4+reg  [verified m89/m91]
    float* ybase = y + (size_t)b * 512 * 512;
    const int rowb = tm * 128 + wm + (lane >> 4) * 4;
    const int colb = tn * 128 + wn + (lane & 15);
#pragma unroll
    for (int i = 0; i < 4; ++i) {
#pragma unroll
        for (int jj = 0; jj < 4; ++jj) {
            const int col = colb + jj * 16;
            const int r0  = rowb + i * 16;
#pragma unroll
            for (int r = 0; r < 4; ++r)
                __builtin_nontemporal_store(acc[i][jj][r],
                    ybase + (size_t)(r0 + r) * 512 + col);
        }
    }
}

extern "C" void kernel_launch(void* const* d_in, const int* in_sizes, int n_in,
                              void* d_out, int out_size, void* d_ws, size_t ws_size,
                              hipStream_t stream) {
    const float* x = (const float*)d_in[0];
    float* yout = (float*)d_out;
    unsigned short* xb = (unsigned short*)d_ws;   // 64*512*256 bf16 = 16 MB

    center_bf16<<<8192, 256, 0, stream>>>(x, xb);
    syrk_bf16<<<1024, 256, 0, stream>>>(xb, yout);
}

// Round 4
// 110.467 us; speedup vs baseline: 1.0080x; 1.0080x over previous
//
#include <hip/hip_runtime.h>
#include <stdint.h>

// covpool: y[b] = (1/M) Xc Xc^T = (1/M) X X^T - mu mu^T   (M=256, rank-1 correction!)
// Single fused kernel: stage x/16 as bf16 into LDS (ds_write, XOR-swizzled slots),
// accumulate exact fp32 row sums during staging, bf16 MFMA SYRK, epilogue subtracts
// mu_r*mu_c. No workspace, no second kernel, no centering pass.

typedef __attribute__((ext_vector_type(8))) short bf16x8;   // 8 bf16 = 4 VGPRs
typedef __attribute__((ext_vector_type(4))) float f32x4;

static __device__ __forceinline__ unsigned short f2bf(float f) {
    union { float f; uint32_t u; } c; c.f = f;
    uint32_t u = c.u;
    return (unsigned short)((u + 0x7FFFu + ((u >> 16) & 1u)) >> 16);  // RNE
}

__global__ __launch_bounds__(256) void covpool_fused(const float* __restrict__ x,
                                                     float* __restrict__ y) {
    __shared__ __align__(16) unsigned short As[128 * 32];  // [row][slot], slot = chunk ^ ((row>>1)&3)
    __shared__ __align__(16) unsigned short Bs[128 * 32];
    __shared__ __align__(16) float muA[128];
    __shared__ __align__(16) float muB[128];

    // XCD swizzle: batch b's 16 tiles all land on XCD b>>3 (L2 locality for x slab)
    const int xcd  = blockIdx.x & 7;
    const int j    = blockIdx.x >> 3;        // 0..127
    const int b    = xcd * 8 + (j >> 4);     // 0..63
    const int tile = j & 15;
    const int tm = tile >> 2, tn = tile & 3;
    const bool diag = (tm == tn);            // block-uniform

    const float* Ag = x + ((size_t)b * 512 + tm * 128) * 256;
    const float* Bg = x + ((size_t)b * 512 + tn * 128) * 256;

    const int tid  = threadIdx.x;
    const int lane = tid & 63;
    const int wave = tid >> 6;
    const int wm = (wave >> 1) * 64;
    const int wn = (wave & 1) * 64;

    f32x4 acc[4][4] = {};
    float pA[2] = {0.f, 0.f}, pB[2] = {0.f, 0.f};  // per-thread row-sum partials

    const int rl  = lane & 15;
    const int swl = ((lane >> 4) ^ ((rl >> 1) & 3)) * 8;  // swizzled read slot (shorts)
    const int srow   = tid >> 2;   // staging row (t adds 64)
    const int schunk = tid & 3;    // global 8-float chunk within BK=32

    for (int kk = 0; kk < 256; kk += 32) {
        __syncthreads();           // protect LDS from prev-iter readers
#pragma unroll
        for (int t = 0; t < 2; ++t) {
            const int row  = t * 64 + srow;
            const int slot = schunk ^ ((row >> 1) & 3);
            {   // A tile
                const float* g = Ag + (size_t)row * 256 + kk + schunk * 8;
                f32x4 v0 = *(const f32x4*)g;
                f32x4 v1 = *(const f32x4*)(g + 4);
                v0 *= 0.0625f; v1 *= 0.0625f;
                pA[t] += (v0.x + v0.y + v0.z + v0.w) + (v1.x + v1.y + v1.z + v1.w);
                bf16x8 o;
                o[0] = (short)f2bf(v0.x); o[1] = (short)f2bf(v0.y);
                o[2] = (short)f2bf(v0.z); o[3] = (short)f2bf(v0.w);
                o[4] = (short)f2bf(v1.x); o[5] = (short)f2bf(v1.y);
                o[6] = (short)f2bf(v1.z); o[7] = (short)f2bf(v1.w);
                *(bf16x8*)(As + row * 32 + slot * 8) = o;
            }
            if (!diag) {  // B tile
                const float* g = Bg + (size_t)row * 256 + kk + schunk * 8;
                f32x4 v0 = *(const f32x4*)g;
                f32x4 v1 = *(const f32x4*)(g + 4);
                v0 *= 0.0625f; v1 *= 0.0625f;
                pB[t] += (v0.x + v0.y + v0.z + v0.w) + (v1.x + v1.y + v1.z + v1.w);
                bf16x8 o;
                o[0] = (short)f2bf(v0.x); o[1] = (short)f2bf(v0.y);
                o[2] = (short)f2bf(v0.z); o[3] = (short)f2bf(v0.w);
                o[4] = (short)f2bf(v1.x); o[5] = (short)f2bf(v1.y);
                o[6] = (short)f2bf(v1.z); o[7] = (short)f2bf(v1.w);
                *(bf16x8*)(Bs + row * 32 + slot * 8) = o;
            }
        }
        __syncthreads();

        const unsigned short* Bsrc = diag ? As : Bs;
        bf16x8 af[4], bfr[4];
#pragma unroll
        for (int i = 0; i < 4; ++i)
            af[i] = *(const bf16x8*)(As + (wm + i * 16 + rl) * 32 + swl);
#pragma unroll
        for (int jj = 0; jj < 4; ++jj)
            bfr[jj] = *(const bf16x8*)(Bsrc + (wn + jj * 16 + rl) * 32 + swl);
#pragma unroll
        for (int i = 0; i < 4; ++i)
#pragma unroll
            for (int jj = 0; jj < 4; ++jj)
                acc[i][jj] = __builtin_amdgcn_mfma_f32_16x16x32_bf16(
                    af[i], bfr[jj], acc[i][jj], 0, 0, 0);
    }

    // Row means: 4 staging threads (chunks) per row -> shuffle-reduce, mu = rowsum/16
    // (staged values are x/16, so mu = (sum x)/256 = rowsum/16; y = acc - mu_r*mu_c)
#pragma unroll
    for (int t = 0; t < 2; ++t) {
        float s = pA[t];
        s += __shfl_xor(s, 1, 64); s += __shfl_xor(s, 2, 64);
        if ((tid & 3) == 0) muA[t * 64 + srow] = s * 0.0625f;
        if (!diag) {
            float sb = pB[t];
            sb += __shfl_xor(sb, 1, 64); sb += __shfl_xor(sb, 2, 64);
            if ((tid & 3) == 0) muB[t * 64 + srow] = sb * 0.0625f;
        }
    }
    __syncthreads();

    // Epilogue: C/D layout col=lane&15, row=(lane>>4)*4+reg  [verified m89/m91]
    const float* muBp = diag ? muA : muB;
    float* ybase = y + (size_t)b * 512 * 512;
    const int rowb = tm * 128 + wm + (lane >> 4) * 4;
    const int colb = tn * 128 + wn + rl;
    float cB[4];
#pragma unroll
    for (int jj = 0; jj < 4; ++jj) cB[jj] = muBp[wn + jj * 16 + rl];
#pragma unroll
    for (int i = 0; i < 4; ++i) {
        const f32x4 ma = *(const f32x4*)&muA[wm + i * 16 + (lane >> 4) * 4];
#pragma unroll
        for (int jj = 0; jj < 4; ++jj) {
            const int col = colb + jj * 16;
            const int r0  = rowb + i * 16;
#pragma unroll
            for (int r = 0; r < 4; ++r)
                ybase[(size_t)(r0 + r) * 512 + col] = acc[i][jj][r] - ma[r] * cB[jj];
        }
    }
}

extern "C" void kernel_launch(void* const* d_in, const int* in_sizes, int n_in,
                              void* d_out, int out_size, void* d_ws, size_t ws_size,
                              hipStream_t stream) {
    const float* x = (const float*)d_in[0];
    float* yout = (float*)d_out;
    (void)d_ws; (void)ws_size;
    covpool_fused<<<1024, 256, 0, stream>>>(x, yout);
}

// Round 5
// 101.761 us; speedup vs baseline: 1.0942x; 1.0855x over previous
//
#include <hip/hip_runtime.h>
#include <stdint.h>

// covpool: y[b] = (1/M) Xc Xc^T = (1/16 X)(1/16 X)^T - mu mu^T   (M=256)
// One fused kernel. Upper-triangular tiles only (y symmetric): 10 tiles/batch,
// off-diag blocks store both orientations via an LDS transpose buffer.
// K-loop register-prefetches the next chunk so global latency overlaps MFMA.

typedef __attribute__((ext_vector_type(8))) short bf16x8;   // 8 bf16 = 4 VGPRs
typedef __attribute__((ext_vector_type(4))) float f32x4;

static __device__ __forceinline__ unsigned short f2bf(float f) {
    union { float f; uint32_t u; } c; c.f = f;
    uint32_t u = c.u;
    return (unsigned short)((u + 0x7FFFu + ((u >> 16) & 1u)) >> 16);  // RNE
}

static __device__ __forceinline__ void cvt_store(f32x4 v0, f32x4 v1, float* psum,
                                                 unsigned short* dst) {
    v0 *= 0.0625f; v1 *= 0.0625f;
    *psum += (v0.x + v0.y + v0.z + v0.w) + (v1.x + v1.y + v1.z + v1.w);
    bf16x8 o;
    o[0] = (short)f2bf(v0.x); o[1] = (short)f2bf(v0.y);
    o[2] = (short)f2bf(v0.z); o[3] = (short)f2bf(v0.w);
    o[4] = (short)f2bf(v1.x); o[5] = (short)f2bf(v1.y);
    o[6] = (short)f2bf(v1.z); o[7] = (short)f2bf(v1.w);
    *(bf16x8*)dst = o;
}

__global__ __launch_bounds__(256) void covpool_fused(const float* __restrict__ x,
                                                     float* __restrict__ y) {
    __shared__ __align__(16) unsigned short As[128 * 32];  // [row][slot], slot=chunk^((row>>1)&3)
    __shared__ __align__(16) unsigned short Bs[128 * 32];
    __shared__ __align__(16) float Ep[32 * 132];           // epilogue transpose buffer
    __shared__ float muA[128];
    __shared__ float muB[128];

    // 640 blocks: XCD swizzle (blockIdx%8 -> XCD), 8 batches/XCD x 10 upper-tri tiles
    const int xcd = blockIdx.x & 7;
    const int j   = blockIdx.x >> 3;         // 0..79
    const int b   = xcd * 8 + j / 10;        // 0..63
    const int t10 = j % 10;
    // nibble LUT: t10 -> (tm<<2|tn) over {(0,0)..(3,3), tm<=tn}
    const unsigned code = (unsigned)((0xFBA7653210ULL >> (4 * t10)) & 15ULL);
    const int tm = code >> 2, tn = code & 3;
    const bool diag = (tm == tn);

    const float* Ag = x + ((size_t)b * 512 + tm * 128) * 256;
    const float* Bg = x + ((size_t)b * 512 + tn * 128) * 256;

    const int tid  = threadIdx.x;
    const int lane = tid & 63;
    const int wave = tid >> 6;
    const int wm = (wave >> 1) * 64;
    const int wn = (wave & 1) * 64;

    f32x4 acc[4][4] = {};
    float pA[2] = {0.f, 0.f}, pB[2] = {0.f, 0.f};

    const int rl  = lane & 15;
    const int q   = lane >> 4;
    const int swl = (q ^ ((rl >> 1) & 3)) * 8;   // swizzled read slot (shorts)
    const int srow = tid >> 2, schunk = tid & 3;

    // prefetch kk=0 into registers
    f32x4 a0[2], a1[2], b0[2], b1[2];
#pragma unroll
    for (int t = 0; t < 2; ++t) {
        const float* g = Ag + (size_t)(t * 64 + srow) * 256 + schunk * 8;
        a0[t] = *(const f32x4*)g; a1[t] = *(const f32x4*)(g + 4);
        if (!diag) {
            const float* h = Bg + (size_t)(t * 64 + srow) * 256 + schunk * 8;
            b0[t] = *(const f32x4*)h; b1[t] = *(const f32x4*)(h + 4);
        }
    }

    for (int kk = 0; kk < 256; kk += 32) {
        __syncthreads();                     // prev iter's fragment reads done
#pragma unroll
        for (int t = 0; t < 2; ++t) {
            const int row  = t * 64 + srow;
            const int slot = schunk ^ ((row >> 1) & 3);
            cvt_store(a0[t], a1[t], &pA[t], As + row * 32 + slot * 8);
            if (!diag) cvt_store(b0[t], b1[t], &pB[t], Bs + row * 32 + slot * 8);
        }
        __syncthreads();
        if (kk < 224) {                      // issue next chunk; waited at next cvt_store
#pragma unroll
            for (int t = 0; t < 2; ++t) {
                const float* g = Ag + (size_t)(t * 64 + srow) * 256 + (kk + 32) + schunk * 8;
                a0[t] = *(const f32x4*)g; a1[t] = *(const f32x4*)(g + 4);
                if (!diag) {
                    const float* h = Bg + (size_t)(t * 64 + srow) * 256 + (kk + 32) + schunk * 8;
                    b0[t] = *(const f32x4*)h; b1[t] = *(const f32x4*)(h + 4);
                }
            }
        }
        const unsigned short* Bsrc = diag ? As : Bs;
        bf16x8 af[4], bfr[4];
#pragma unroll
        for (int i = 0; i < 4; ++i)
            af[i] = *(const bf16x8*)(As + (wm + i * 16 + rl) * 32 + swl);
#pragma unroll
        for (int jj = 0; jj < 4; ++jj)
            bfr[jj] = *(const bf16x8*)(Bsrc + (wn + jj * 16 + rl) * 32 + swl);
#pragma unroll
        for (int i = 0; i < 4; ++i)
#pragma unroll
            for (int jj = 0; jj < 4; ++jj)
                acc[i][jj] = __builtin_amdgcn_mfma_f32_16x16x32_bf16(
                    af[i], bfr[jj], acc[i][jj], 0, 0, 0);
    }

    // row means: 4 staging threads per row; staged vals are x/16 so mu = rowsum/16
#pragma unroll
    for (int t = 0; t < 2; ++t) {
        float s = pA[t];
        s += __shfl_xor(s, 1, 64); s += __shfl_xor(s, 2, 64);
        if (schunk == 0) muA[t * 64 + srow] = s * 0.0625f;
        if (!diag) {
            float sb = pB[t];
            sb += __shfl_xor(sb, 1, 64); sb += __shfl_xor(sb, 2, 64);
            if (schunk == 0) muB[t * 64 + srow] = sb * 0.0625f;
        }
    }
    const float* muBp = diag ? muA : muB;
    float* yb = y + (size_t)b * 512 * 512;

    // Epilogue in 4 chunks of 32 rows through Ep[32][132]:
    //   owner waves (wm matching) write acc - mu_r*mu_c; all waves store coalesced
    //   f32x4 runs, plus the transposed (mirror) tile for off-diag blocks.
#pragma unroll
    for (int c = 0; c < 4; ++c) {
        __syncthreads();                     // Ep free; mu ready (first iter)
        if ((wave >> 1) == (c >> 1)) {       // rows 32c..32c+31 live in this wave's acc
            const int ii0 = 2 * (c & 1);
#pragma unroll
            for (int ii = 0; ii < 2; ++ii) {
                const int i = ii0 + ii;
#pragma unroll
                for (int jj = 0; jj < 4; ++jj) {
                    const int col = wn + jj * 16 + rl;
                    const float mb = muBp[col];
#pragma unroll
                    for (int r = 0; r < 4; ++r) {
                        const int row = wm + i * 16 + q * 4 + r;
                        Ep[(ii * 16 + q * 4 + r) * 132 + col] = acc[i][jj][r] - muA[row] * mb;
                    }
                }
            }
        }
        __syncthreads();
        // normal orientation: 512B-contiguous dwordx4 runs
#pragma unroll
        for (int v = 0; v < 4; ++v) {
            const int flat = v * 256 + tid;          // 0..1023
            const int rloc = flat >> 5, c4 = flat & 31;
            f32x4 val = *(const f32x4*)(Ep + rloc * 132 + c4 * 4);
            *(f32x4*)(yb + (size_t)(tm * 128 + c * 32 + rloc) * 512 + tn * 128 + c4 * 4) = val;
        }
        if (!diag) {  // mirror: y[col][row] = same value, read Ep transposed
#pragma unroll
            for (int v = 0; v < 4; ++v) {
                const int id = v * 256 + tid;        // 0..1023
                const int cc = id >> 3, g = id & 7;  // cc: tile col, g: 4-row group
                f32x4 val;
#pragma unroll
                for (int e = 0; e < 4; ++e)
                    val[e] = Ep[(g * 4 + e) * 132 + cc];
                *(f32x4*)(yb + (size_t)(tn * 128 + cc) * 512 + tm * 128 + c * 32 + g * 4) = val;
            }
        }
    }
}

extern "C" void kernel_launch(void* const* d_in, const int* in_sizes, int n_in,
                              void* d_out, int out_size, void* d_ws, size_t ws_size,
                              hipStream_t stream) {
    const float* x = (const float*)d_in[0];
    float* yout = (float*)d_out;
    (void)d_ws; (void)ws_size;
    covpool_fused<<<640, 256, 0, stream>>>(x, yout);
}